// Round 3
// baseline (4561.077 us; speedup 1.0000x reference)
//
#include <hip/hip_runtime.h>
#include <stdint.h>

// SPINN thin-stack TreeLSTM, MI355X, round 9: VGPR-relief + in-P1 exchange.
// Pair (g2) = blocks (2g2, 2g2+1); block sl owns 64 H-dims (320 gate cols).
// Changes vs round 8 (theory: W was AGPR-split -> v_accvgpr_read storm; P2
// poll + barrier vmcnt drains ate the rest):
//  (1) W: 28 K-rows/wave in VGPRs (140 f32/thr) + 12 K-rows/wave in LDS
//      (96x320 = 120KB) -> arch-VGPR resident, no AGPR round-trips.
//  (2) f32x2 packed FMA (v_pk_fma_f32) halves GEMM issue.
//  (3) Block-local K-permutation puts partner-hr at k in [256,320); wave 7
//      polls partner h(t-1) DURING P1 (published one step earlier -> flight
//      hidden), deposits xs[cur], releases LDS flag; only waves 6,7 (owners
//      of k>=256) spin. P2 has no poll.
//  (4) gpq via ds_add_f32 into bias-pre-init buffer: cell reads 5 vals.
//  (5) raw "lgkmcnt(0); s_barrier" (no vmcnt drain) -> global stores retire
//      in the shadow of the next phase.
// xs layout (block-local k): [0,64) label | [64,128) hl-own | [128,192)
// hl-partner | [192,256) hr-own | [256,320) hr-partner.

#define D     512
#define HD    128
#define LD    64
#define NTHR  512

typedef unsigned long long u64t;
typedef float f32x2 __attribute__((ext_vector_type(2)));

__device__ __forceinline__ float sigf(float x){ return 1.0f/(1.0f+__expf(-x)); }
__device__ __forceinline__ float tanh_(float x){ return 1.0f-2.0f/(__expf(2.0f*x)+1.0f); }
__device__ __forceinline__ u64t gld64(const float* p){
  return __hip_atomic_load((const u64t*)p, __ATOMIC_RELAXED, __HIP_MEMORY_SCOPE_AGENT);
}
__device__ __forceinline__ u64t gld64r(const u64t* p){
  return __hip_atomic_load(p, __ATOMIC_RELAXED, __HIP_MEMORY_SCOPE_AGENT);
}
__device__ __forceinline__ void gst32(float* p, float v){
  __hip_atomic_store(p, v, __ATOMIC_RELAXED, __HIP_MEMORY_SCOPE_AGENT);
}
__device__ __forceinline__ void gst64r(u64t* p, u64t v){
  __hip_atomic_store(p, v, __ATOMIC_RELAXED, __HIP_MEMORY_SCOPE_AGENT);
}
__device__ __forceinline__ u64t packw(float v, unsigned tg){
  return ((u64t)tg << 32) | (u64t)__float_as_uint(v);
}
__device__ __forceinline__ float loww(u64t w){
  return __uint_as_float((unsigned)(w & 0xffffffffu));
}
__device__ __forceinline__ int permrow(int k, int sl){
  // block-local k -> global W row (xs layout above)
  const int ps = sl^1;
  if (k < 64)  return k;
  if (k < 128) return 64  + sl*64 + (k-64);
  if (k < 192) return 64  + ps*64 + (k-128);
  if (k < 256) return 192 + sl*64 + (k-192);
  return 192 + ps*64 + (k-256);
}

// barrier WITHOUT vmcnt drain: LDS deps only (global stores retire async)
#define BARRIER() __asm__ volatile("s_waitcnt lgkmcnt(0)\n\ts_barrier" ::: "memory")

// 4 K-rows of GEMM with given W fragments (all f32x2 packed)
#define GEMM4(GETW) { \
  const float4 x0_ = *(const float4*)&xs[cur][0][kbase]; \
  const float4 x1_ = *(const float4*)&xs[cur][1][kbase]; \
  const float xa0_[4] = {x0_.x,x0_.y,x0_.z,x0_.w}; \
  const float xa1_[4] = {x1_.x,x1_.y,x1_.z,x1_.w}; \
  _Pragma("unroll") \
  for (int jj=0;jj<4;++jj){ \
    f32x2 wA_, wB_; float wu_; GETW; \
    const f32x2 b0_ = {xa0_[jj], xa0_[jj]}; \
    const f32x2 b1_ = {xa1_[jj], xa1_[jj]}; \
    accA0 = __builtin_elementwise_fma(wA_, b0_, accA0); \
    accB0 = __builtin_elementwise_fma(wB_, b0_, accB0); \
    u0 = __builtin_fmaf(wu_, xa0_[jj], u0); \
    accA1 = __builtin_elementwise_fma(wA_, b1_, accA1); \
    accB1 = __builtin_elementwise_fma(wB_, b1_, accB1); \
    u1 = __builtin_fmaf(wu_, xa1_[jj], u1); \
  } }

__global__ __launch_bounds__(NTHR,2) void spinn_kernel(
    const int* __restrict__ trans, const int* __restrict__ labels,
    const float* __restrict__ emb, const float* __restrict__ W,
    const float* __restrict__ bias, const float* __restrict__ leaf,
    float* __restrict__ out, u64t* __restrict__ ring,
    float* __restrict__ rec, float* __restrict__ cown)
{
  const int bid = blockIdx.x;
  const int g2 = bid>>1, sl = bid&1, ps = sl^1;
  const int gb0 = g2*2;
  const int tid = threadIdx.x;
  const int kg = tid>>6, lane = tid&63;
  const int cq = lane;

  __shared__ __align__(16) float lw[96][320];       // LDS-resident W rows
  __shared__ __align__(16) float xs[2][2][320];     // [buf][b][k]
  __shared__ __align__(16) float gpq[2][2][320];    // gate sums (bias-preinit)
  __shared__ float bsl[320];
  __shared__ float lshd[HD];
  __shared__ float clb[2][2][64];
  __shared__ uint8_t mS[D][2];
  __shared__ short liA[D][2];
  __shared__ unsigned short stk_[2][D];
  __shared__ int xflag;

  // --- W slice: 28 reg rows/wave (f32x2 pairs) + gather cols ---
  f32x2 wrA[28], wrB[28]; float wr1[28];
  const int gq = (cq>>4)*128 + sl*64 + ((cq*4)&63);  // quad base (gates 0-3)
  const int gu = 512 + sl*64 + cq;                   // u-gate col
  {
#pragma unroll
    for (int j=0;j<28;++j){
      const int R = permrow(kg*40+j, sl);
      const float4 w4 = *(const float4*)(W + (size_t)R*640 + gq);
      f32x2 a; a.x = w4.x; a.y = w4.y; wrA[j] = a;
      f32x2 b; b.x = w4.z; b.y = w4.w; wrB[j] = b;
      wr1[j] = W[(size_t)R*640 + gu];
    }
  }
  // LDS W rows: per wave rows j=28..39 -> lw[kg*12 + (j-28)][c]
  for (int idx = tid; idx < 96*320; idx += NTHR){
    const int r = idx/320, c = idx - r*320;
    const int kg_ = r/12, m = r - kg_*12;
    const int R = permrow(kg_*40 + 28 + m, sl);
    const int gc = (c < 256) ? ((c>>6)*128 + sl*64 + (c&63))
                             : (512 + sl*64 + (c-256));
    lw[r][c] = W[(size_t)R*640 + gc];
  }
  if (tid < 320){
    const int c = tid;
    const int gc = (c < 256) ? ((c>>6)*128 + sl*64 + (c&63))
                             : (512 + sl*64 + (c-256));
    bsl[c] = bias[gc];
  }
  if (tid < HD) lshd[tid] = leaf[tid];
  if (tid == NTHR-1) xflag = 0;
  if (tid < 2){   // precompute (mask, li); ri == t-1 always on a reduce
    int b = tid, p = 0;
    for (int t=0;t<D;++t){
      int m = trans[t*256 + gb0 + b];
      short li = 0;
      if (m) li = (short)stk_[b][p-2];
      mS[t][b] = (uint8_t)m; liA[t][b] = li;
      int np = p - 2*m; stk_[b][np] = (unsigned short)t; p = np+1;
    }
  }
  __syncthreads();

  // --- prefill xs[0] (mask(0)==0) + gpq[0]=bias ---
  for (int idx = tid; idx < 640; idx += NTHR){
    const int b = (idx >= 320) ? 1 : 0;
    const int r = idx - b*320;
    float v;
    if (r < 64)       v = emb[(size_t)labels[gb0 + b]*LD + r];
    else if (r < 128) v = lshd[sl*64 + (r-64)];
    else if (r < 192) v = lshd[ps*64 + (r-128)];
    else if (r < 256) v = lshd[sl*64 + (r-192)];
    else              v = lshd[ps*64 + (r-256)];
    xs[0][b][r] = v;
  }
  for (int c = tid; c < 640; c += NTHR){
    const int b = (c >= 320) ? 1 : 0;
    gpq[0][b][c - b*320] = bsl[c - b*320];
  }
  __syncthreads();

  float ccprev = 0.f;   // own c[t-1][b][dl] (cell threads only)

  for (int t=0;t<D;++t){
    const int cur = t&1, nxt = cur^1;

    // ================= P1: GEMM (+ wave7 exchange, wave6 gated) ===========
    f32x2 accA0 = {0.f,0.f}, accB0 = {0.f,0.f};
    f32x2 accA1 = {0.f,0.f}, accB1 = {0.f,0.f};
    float u0 = 0.f, u1 = 0.f;

    if (kg == 7){
      // poll partner h(t-1) (published at partner P2(t-1): one step of flight
      // already elapsed), deposit into xs[cur] hr-partner, release flag.
      if (t > 0){
        const u64t* rp = ring + ((((size_t)((t-1)&7))*128 + g2)*2 + ps)*128 + lane*2;
        const unsigned want = (unsigned)t;   // tag = (t-1)+1
        u64t w0 = 0, w1 = 0; int it = 0;
        for (;;){
          w0 = gld64r(rp); w1 = gld64r(rp+1);
          const int ok = ((unsigned)(w0>>32) == want) & ((unsigned)(w1>>32) == want);
          if (__all(ok)) break;
          __builtin_amdgcn_s_sleep(1);
          if (++it > (1<<20)) break;   // safety: hang -> wrong answer
        }
        const int b = lane>>5, jj = lane&31;
        if (mS[t][b]){
          xs[cur][b][256+jj*2]   = loww(w0);
          xs[cur][b][256+jj*2+1] = loww(w1);
        } else {
          xs[cur][b][256+jj*2]   = lshd[ps*64+jj*2];
          xs[cur][b][256+jj*2+1] = lshd[ps*64+jj*2+1];
        }
      }
      __hip_atomic_store(&xflag, t+1, __ATOMIC_RELEASE, __HIP_MEMORY_SCOPE_WORKGROUP);
    }

    // reg groups 0-3 (rows kg*40 .. +15): safe for waves 0-6 (k<256)
#pragma unroll
    for (int j4=0;j4<4;++j4){
      const int kbase = kg*40 + j4*4;
      GEMM4({ wA_ = wrA[j4*4+jj]; wB_ = wrB[j4*4+jj]; wu_ = wr1[j4*4+jj]; });
    }
    if (kg == 6){  // rows >=256 need wave7's deposit
      int it = 0;
      while (__hip_atomic_load(&xflag, __ATOMIC_ACQUIRE, __HIP_MEMORY_SCOPE_WORKGROUP) < t+1){
        __builtin_amdgcn_s_sleep(1);
        if (++it > (1<<22)) break;
      }
    }
    // reg groups 4-6 (rows 16-27)
#pragma unroll
    for (int j4=4;j4<7;++j4){
      const int kbase = kg*40 + j4*4;
      GEMM4({ wA_ = wrA[j4*4+jj]; wB_ = wrB[j4*4+jj]; wu_ = wr1[j4*4+jj]; });
    }
    // LDS groups 7-9 (rows 28-39, W from lw)
#pragma unroll
    for (int j4=7;j4<10;++j4){
      const int kbase = kg*40 + j4*4;
      GEMM4({
        const int r_ = kg*12 + (j4-7)*4 + jj;
        const float4 wq_ = *(const float4*)&lw[r_][cq*4];
        const float wuu_ = lw[r_][256+cq];
        f32x2 ta_; ta_.x = wq_.x; ta_.y = wq_.y; wA_ = ta_;
        f32x2 tb_; tb_.x = wq_.z; tb_.y = wq_.w; wB_ = tb_;
        wu_ = wuu_;
      });
    }
    // accumulate into gpq[cur] (bias-preinit) via LDS f32 atomics
    {
      float* g0 = &gpq[cur][0][0];
      float* g1 = &gpq[cur][1][0];
      __hip_atomic_fetch_add(g0 + cq*4+0, accA0.x, __ATOMIC_RELAXED, __HIP_MEMORY_SCOPE_WORKGROUP);
      __hip_atomic_fetch_add(g0 + cq*4+1, accA0.y, __ATOMIC_RELAXED, __HIP_MEMORY_SCOPE_WORKGROUP);
      __hip_atomic_fetch_add(g0 + cq*4+2, accB0.x, __ATOMIC_RELAXED, __HIP_MEMORY_SCOPE_WORKGROUP);
      __hip_atomic_fetch_add(g0 + cq*4+3, accB0.y, __ATOMIC_RELAXED, __HIP_MEMORY_SCOPE_WORKGROUP);
      __hip_atomic_fetch_add(g0 + 256+cq,  u0,     __ATOMIC_RELAXED, __HIP_MEMORY_SCOPE_WORKGROUP);
      __hip_atomic_fetch_add(g1 + cq*4+0, accA1.x, __ATOMIC_RELAXED, __HIP_MEMORY_SCOPE_WORKGROUP);
      __hip_atomic_fetch_add(g1 + cq*4+1, accA1.y, __ATOMIC_RELAXED, __HIP_MEMORY_SCOPE_WORKGROUP);
      __hip_atomic_fetch_add(g1 + cq*4+2, accB1.x, __ATOMIC_RELAXED, __HIP_MEMORY_SCOPE_WORKGROUP);
      __hip_atomic_fetch_add(g1 + cq*4+3, accB1.y, __ATOMIC_RELAXED, __HIP_MEMORY_SCOPE_WORKGROUP);
      __hip_atomic_fetch_add(g1 + 256+cq,  u1,     __ATOMIC_RELAXED, __HIP_MEMORY_SCOPE_WORKGROUP);
    }
    BARRIER();

    // ================= P2: cell | prefetch | gpq-init =====================
    if (tid < 128){
      const int b = tid>>6, dl = tid&63, gd = sl*64+dl;
      const int m = mS[t][b];
      float s[5];
#pragma unroll
      for (int g=0; g<4; ++g) s[g] = gpq[cur][b][g*64+dl];
      s[4] = gpq[cur][b][256+dl];
      const float cl_ = m ? clb[cur][b][dl] : lshd[gd];
      const float cr_ = m ? ccprev : lshd[gd];      // ri == t-1: own prev c
      const float cc = sigf(s[0])*tanh_(s[4]) + sigf(s[1])*cl_ + sigf(s[2])*cr_;
      const float hh = sigf(s[3])*tanh_(cc);
      ccprev = cc;
      // publish self-tagged h FIRST (partner polls it at its P1(t+1))
      gst64r(ring + (((size_t)(t&7)*128 + g2)*2 + sl)*128 + tid,
             packw(hh, (unsigned)(t+1)));
      const size_t ro = (((size_t)t*128 + g2)*2 + sl)*128 + b*64 + dl;
      gst32(rec + ro, hh);
      gst32(cown + ro, cc);
      if (t == D-1){
        out[(size_t)(gb0+b)*HD + gd] = cc;
        out[(size_t)256*HD + (size_t)(gb0+b)*HD + gd] = hh;
      } else {
        xs[nxt][b][192+dl] = mS[t+1][b] ? hh : lshd[gd];   // own hr for t+1
      }
      if (t+2 < D && mS[t+2][b] && liA[t+2][b] == t){
        xs[cur][b][64+dl] = hh;     // own hl for t+2 (li==t case)
        clb[cur][b][dl]   = cc;     // own cl for t+2
      }
    } else if (kg == 2){            // emb(t+1) -> label slots
      if (t+1 < D){
        const int b = lane>>5, jj = lane&31;
        const int row = labels[(t+1)*256 + gb0 + b];
        const float2 ev = *(const float2*)(emb + (size_t)row*LD + jj*2);
        xs[nxt][b][jj*2]   = ev.x;
        xs[nxt][b][jj*2+1] = ev.y;
      }
    } else if (kg == 3){            // own-half hl/cl for t+1
      if (t+1 < D){
        const int b = lane>>5, jj = lane&31;
        const int m1 = mS[t+1][b]; const int li = liA[t+1][b];
        if (m1){
          if (li <= t-1){
            const size_t ro = (((size_t)li*128+g2)*2 + sl)*128 + b*64 + jj*2;
            union{u64t u; float f[2];} h_, c_;
            h_.u = gld64(rec + ro);
            c_.u = gld64(cown + ro);
            xs[nxt][b][64+jj*2]   = h_.f[0];
            xs[nxt][b][64+jj*2+1] = h_.f[1];
            clb[nxt][b][jj*2]     = c_.f[0];
            clb[nxt][b][jj*2+1]   = c_.f[1];
          }
          // li == t: cell@t wrote xs[nxt... wait cell writes buffer parity t+2
          // (li==t case targets step t+2; for t+1, li<=t-1 always)
        } else {
          xs[nxt][b][64+jj*2]   = lshd[sl*64+jj*2];
          xs[nxt][b][64+jj*2+1] = lshd[sl*64+jj*2+1];
          clb[nxt][b][jj*2]     = lshd[sl*64+jj*2];
          clb[nxt][b][jj*2+1]   = lshd[sl*64+jj*2+1];
        }
      }
    } else if (kg == 4){            // partner-half hl for t+1
      if (t+1 < D){
        const int b = lane>>5, jj = lane&31;
        const int m1 = mS[t+1][b]; const int li = liA[t+1][b];
        if (m1){
          if (li <= t-2){
            const size_t ro = (((size_t)li*128+g2)*2 + ps)*128 + b*64 + jj*2;
            union{u64t u; float f[2];} h_;
            h_.u = gld64(rec + ro);
            xs[nxt][b][128+jj*2]   = h_.f[0];
            xs[nxt][b][128+jj*2+1] = h_.f[1];
          } else {                  // li == t-1: ring slot confirmed by wave7@P1(t)
            const u64t* rp = ring + (((size_t)((t-1)&7)*128 + g2)*2 + ps)*128
                             + b*64 + jj*2;
            xs[nxt][b][128+jj*2]   = loww(gld64r(rp));
            xs[nxt][b][128+jj*2+1] = loww(gld64r(rp+1));
          }
        } else {
          xs[nxt][b][128+jj*2]   = lshd[ps*64+jj*2];
          xs[nxt][b][128+jj*2+1] = lshd[ps*64+jj*2+1];
        }
      }
    } else if (kg == 5 || kg == 6){ // gpq[nxt] = bias for t+1
      const int ii = tid - 320;     // 0..127
#pragma unroll
      for (int q=0;q<5;++q){
        const int c = ii + q*128;   // 0..639
        const int b = (c >= 320) ? 1 : 0;
        gpq[nxt][b][c - b*320] = bsl[c - b*320];
      }
    }
    BARRIER();
  }
}

extern "C" void kernel_launch(void* const* d_in, const int* in_sizes, int n_in,
                              void* d_out, int out_size, void* d_ws, size_t ws_size,
                              hipStream_t stream) {
  (void)in_sizes; (void)n_in; (void)out_size; (void)ws_size;
  const int*   trans  = (const int*)d_in[0];
  const int*   labels = (const int*)d_in[1];
  const float* emb    = (const float*)d_in[2];
  const float* W      = (const float*)d_in[3];
  const float* bias   = (const float*)d_in[4];
  const float* leaf   = (const float*)d_in[5];
  float* out = (float*)d_out;

  // ws: [0,8MB)   ring: 8-deep self-tagged h records (tag=t+1; poison/zero
  //               never match; reuse distance 8 steps, pair skew <=1 -> safe)
  //     [8MB,72MB)   rec:  h records (agent stores/loads, >=2-step-old reads)
  //     [72MB,136MB) cown: c records (own-block readers only)
  uint8_t* ws = (uint8_t*)d_ws;
  u64t*  ring = (u64t*)ws;
  float* rec  = (float*)(ws + ((size_t)8<<20));
  float* cown = (float*)(ws + ((size_t)72<<20));

  spinn_kernel<<<dim3(256), dim3(NTHR), 0, stream>>>(
      trans, labels, emb, W, bias, leaf, out, ring, rec, cown);
}

// Round 4
// 2223.852 us; speedup vs baseline: 2.0510x; 2.0510x over previous
//
#include <hip/hip_runtime.h>
#include <stdint.h>

// SPINN thin-stack TreeLSTM, MI355X, round 10: round-8 base + same-XCD pair
// + one-phase-early self-gated exchange + drain-free barriers.
// Pair = (bid, bid^8): same XCD under bid%8 round-robin (perf heuristic only).
// xs K-layout (block-local): [0,64) label | [64,128) hl-own | [128,192)
// hl-partner | [192,256) hr-own | [256,320) hr-partner.  Partner-hr rows are
// owned ONLY by waves 6,7: they poll partner h(t-1) (published at partner's
// P2(t-1) -> flight already elapsed) at start of P1(t), deposit into xs[cur],
// then GEMM their rows. No flags, no other wave ever waits on the exchange.
// Wave 6 GEMMs its own-hr rows (k 240..255) before polling for extra slack.
// Loop barriers are raw "s_waitcnt lgkmcnt(0); s_barrier" (no vmcnt drain):
// ring words are self-tagged, rec/cown readers are >=2 steps behind.
// GEMM lambda + gpq private-row reduce byte-identical to round 8 (verified).

#define D     512
#define HD    128
#define LD    64
#define NTHR  512
#define GPR   328   // gp row stride (floats): 256 quad cols + 64 u cols + pad

typedef unsigned long long u64t;

__device__ __forceinline__ float sigf(float x){ return 1.0f/(1.0f+__expf(-x)); }
__device__ __forceinline__ float tanh_(float x){ return 1.0f-2.0f/(__expf(2.0f*x)+1.0f); }
__device__ __forceinline__ u64t gld64(const float* p){
  return __hip_atomic_load((const u64t*)p, __ATOMIC_RELAXED, __HIP_MEMORY_SCOPE_AGENT);
}
__device__ __forceinline__ u64t gld64r(const u64t* p){
  return __hip_atomic_load(p, __ATOMIC_RELAXED, __HIP_MEMORY_SCOPE_AGENT);
}
__device__ __forceinline__ void gst32(float* p, float v){
  __hip_atomic_store(p, v, __ATOMIC_RELAXED, __HIP_MEMORY_SCOPE_AGENT);
}
__device__ __forceinline__ void gst64r(u64t* p, u64t v){
  __hip_atomic_store(p, v, __ATOMIC_RELAXED, __HIP_MEMORY_SCOPE_AGENT);
}
__device__ __forceinline__ u64t packw(float v, unsigned tg){
  return ((u64t)tg << 32) | (u64t)__float_as_uint(v);
}
__device__ __forceinline__ float loww(u64t w){
  return __uint_as_float((unsigned)(w & 0xffffffffu));
}
__device__ __forceinline__ int permrow(int k, int sl){
  // block-local k -> global W row (xs layout in header)
  const int ps = sl^1;
  if (k < 64)  return k;
  if (k < 128) return 64  + sl*64 + (k-64);
  if (k < 192) return 64  + ps*64 + (k-128);
  if (k < 256) return 192 + sl*64 + (k-192);
  return 192 + ps*64 + (k-256);
}

// loop barrier WITHOUT vmcnt drain (LDS deps only; global stores retire async)
#define BARRIER() __asm__ volatile("s_waitcnt lgkmcnt(0)\n\ts_barrier" ::: "memory")

__global__ __launch_bounds__(NTHR,2) void spinn_kernel(
    const int* __restrict__ trans, const int* __restrict__ labels,
    const float* __restrict__ emb, const float* __restrict__ W,
    const float* __restrict__ bias, const float* __restrict__ leaf,
    float* __restrict__ out, u64t* __restrict__ ring,
    float* __restrict__ rec, float* __restrict__ cown)
{
  const int bid = blockIdx.x;
  const int g2 = ((bid>>4)<<3) | (bid&7);   // pair id: (bid, bid^8) share g2
  const int sl = (bid>>3)&1, ps = sl^1;     // same XCD under bid%8 round-robin
  const int gb0 = g2*2;
  const int tid = threadIdx.x;
  const int kg = tid>>6, lane = tid&63;
  const int cq = lane;

  __shared__ __align__(16) float xs[2][2][320];     // [buf][b][k] (permuted K)
  __shared__ __align__(16) float gpq[16][GPR];      // [(kg*2+b)][col]
  __shared__ float bsl[320];
  __shared__ float lshd[HD];
  __shared__ float clb[2][2][64];
  __shared__ uint8_t mS[D][2];
  __shared__ short liA[D][2];
  __shared__ unsigned short stk_[2][D];

  // --- W slice into registers: 40 permuted K-rows x (4 quad cols + 1 u col) ---
  float4 wr4[40]; float wr1[40];
  {
    const int gq = (cq>>4)*128 + sl*64 + ((cq*4)&63);  // quad base (gates 0-3)
    const int gu = 512 + sl*64 + cq;                   // u-gate col
#pragma unroll
    for (int j=0;j<40;++j){
      const int R = permrow(kg*40 + j, sl);
      wr4[j] = *(const float4*)(W + (size_t)R*640 + gq);
      wr1[j] = W[(size_t)R*640 + gu];
    }
  }
  if (tid < 320){
    int c = tid;
    int gc = (c < 256) ? ((c>>6)*128 + sl*64 + (c&63)) : (512 + sl*64 + (c-256));
    bsl[c] = bias[gc];
  }
  if (tid < HD) lshd[tid] = leaf[tid];
  if (tid < 2){   // precompute (mask, li); ri == t-1 always on a reduce
    int b = tid, p = 0;
    for (int t=0;t<D;++t){
      int m = trans[t*256 + gb0 + b];
      short li = 0;
      if (m) li = (short)stk_[b][p-2];
      mS[t][b] = (uint8_t)m; liA[t][b] = li;
      int np = p - 2*m; stk_[b][np] = (unsigned short)t; p = np+1;
    }
  }
  __syncthreads();

  // --- prefill xs[0] (mask(0)==0 by construction): label + leaf halves ---
  for (int idx = tid; idx < 640; idx += NTHR){
    const int b = (idx >= 320) ? 1 : 0;
    const int r = idx - b*320;
    float v;
    if (r < 64)       v = emb[(size_t)labels[gb0 + b]*LD + r];
    else if (r < 128) v = lshd[sl*64 + (r-64)];
    else if (r < 192) v = lshd[ps*64 + (r-128)];
    else if (r < 256) v = lshd[sl*64 + (r-192)];
    else              v = lshd[ps*64 + (r-256)];
    xs[0][b][r] = v;
  }
  __syncthreads();

  // GEMM over j4 groups [j0,j1) of this wave's 40 K-rows (round-8 body)
  auto gemmr = [&](int cur, int j0, int j1,
                   float4& a0, float4& a1, float& u0, float& u1){
#pragma unroll
    for (int j4=j0;j4<j1;++j4){
      int k = kg*40 + j4*4;
      float4 x0 = *(const float4*)&xs[cur][0][k];   // broadcast (all lanes same)
      float4 x1 = *(const float4*)&xs[cur][1][k];
      float xa0[4] = {x0.x,x0.y,x0.z,x0.w};
      float xa1[4] = {x1.x,x1.y,x1.z,x1.w};
#pragma unroll
      for (int jj=0;jj<4;++jj){
        float4 w = wr4[j4*4+jj];
        float wu = wr1[j4*4+jj];
        a0.x = __builtin_fmaf(w.x, xa0[jj], a0.x);
        a0.y = __builtin_fmaf(w.y, xa0[jj], a0.y);
        a0.z = __builtin_fmaf(w.z, xa0[jj], a0.z);
        a0.w = __builtin_fmaf(w.w, xa0[jj], a0.w);
        a1.x = __builtin_fmaf(w.x, xa1[jj], a1.x);
        a1.y = __builtin_fmaf(w.y, xa1[jj], a1.y);
        a1.z = __builtin_fmaf(w.z, xa1[jj], a1.z);
        a1.w = __builtin_fmaf(w.w, xa1[jj], a1.w);
        u0 = __builtin_fmaf(wu, xa0[jj], u0);
        u1 = __builtin_fmaf(wu, xa1[jj], u1);
      }
    }
  };

  float ccprev = 0.f;   // own c[t-1][b][dl] (cell threads only)

  for (int t=0;t<D;++t){
    const int cur = t&1, nxt = cur^1;

    // ================= P1: GEMM; waves 6,7 self-gate on partner h(t-1) =====
    {
      float4 a0 = {0.f,0.f,0.f,0.f}, a1 = {0.f,0.f,0.f,0.f};
      float u0 = 0.f, u1 = 0.f;

      if (kg <= 5){
        gemmr(cur, 0, 10, a0, a1, u0, u1);          // k < 240: no dependency
      } else if (kg == 6){
        gemmr(cur, 0, 4, a0, a1, u0, u1);           // k 240..255 (own-hr)
        if (t > 0){                                 // poll dl 0..23, b=0,1
          const size_t rb = ((((size_t)((t-1)&7))*128 + g2)*2 + ps)*128;
          const unsigned want = (unsigned)t;        // tag = (t-1)+1
          const bool act = (lane < 24) || (lane >= 32 && lane < 56);
          const int b = lane >> 5;
          const int dl = act ? (b ? lane-32 : lane) : 0;
          const u64t* rp = ring + rb + b*64 + dl;
          u64t w0 = ((u64t)want)<<32; int it = 0;
          for (;;){
            if (act) w0 = gld64r(rp);
            if (__all((unsigned)(w0>>32) == want)) break;
            if (++it > (1<<20)) break;              // safety: hang -> wrong
          }
          if (act)
            xs[cur][b][256+dl] = mS[t][b] ? loww(w0) : lshd[ps*64+dl];
        }
        gemmr(cur, 4, 10, a0, a1, u0, u1);          // k 256..279 (partner-hr)
      } else { // kg == 7
        if (t > 0){                                 // poll dl 24..63, b=0,1
          const size_t rb = ((((size_t)((t-1)&7))*128 + g2)*2 + ps)*128;
          const unsigned want = (unsigned)t;
          const bool act = (lane < 40);
          const int dl = 24 + (act ? lane : 0);
          const u64t* rp0 = ring + rb + dl;         // b = 0
          const u64t* rp1 = ring + rb + 64 + dl;    // b = 1
          u64t w0 = ((u64t)want)<<32, w1 = w0; int it = 0;
          for (;;){
            if (act){ w0 = gld64r(rp0); w1 = gld64r(rp1); }
            if (__all(((unsigned)(w0>>32) == want) &
                      ((unsigned)(w1>>32) == want))) break;
            if (++it > (1<<20)) break;
          }
          if (act){
            xs[cur][0][256+dl] = mS[t][0] ? loww(w0) : lshd[ps*64+dl];
            xs[cur][1][256+dl] = mS[t][1] ? loww(w1) : lshd[ps*64+dl];
          }
        }
        gemmr(cur, 0, 10, a0, a1, u0, u1);          // k 280..319 (own deposit)
      }
      *(float4*)&gpq[kg*2+0][cq*4] = a0;
      *(float4*)&gpq[kg*2+1][cq*4] = a1;
      gpq[kg*2+0][256+cq] = u0;
      gpq[kg*2+1][256+cq] = u1;
    }
    BARRIER();

    // ================= P2: cell (w0-1) || prefetch t+1 (w2-4) ==============
    if (tid < 128){
      const int b = tid>>6, dl = tid&63, gd = sl*64+dl;
      const int m = mS[t][b];
      float s[5];
#pragma unroll
      for (int g=0; g<5; ++g){
        int c = (g<4) ? (g*64+dl) : (256+dl);
        float a = 0.f;
#pragma unroll
        for (int kk=0; kk<8; ++kk) a += gpq[kk*2+b][c];
        s[g] = a + bsl[c];
      }
      const float cl_ = m ? clb[cur][b][dl] : lshd[gd];
      const float cr_ = m ? ccprev : lshd[gd];      // ri == t-1: own prev c
      const float cc = sigf(s[0])*tanh_(s[4]) + sigf(s[1])*cl_ + sigf(s[2])*cr_;
      const float hh = sigf(s[3])*tanh_(cc);
      ccprev = cc;
      // publish self-tagged h FIRST (partner polls it at its P1(t+1))
      gst64r(ring + (((size_t)(t&7)*128 + g2)*2 + sl)*128 + tid,
             packw(hh, (unsigned)(t+1)));
      const size_t ro = (((size_t)t*128 + g2)*2 + sl)*128 + b*64 + dl;
      gst32(rec + ro, hh);
      gst32(cown + ro, cc);
      if (t == D-1){
        out[(size_t)(gb0+b)*HD + gd] = cc;
        out[(size_t)256*HD + (size_t)(gb0+b)*HD + gd] = hh;
      } else {
        xs[nxt][b][192+dl] = mS[t+1][b] ? hh : lshd[gd];   // own hr for t+1
      }
      if (t+2 < D && mS[t+2][b] && liA[t+2][b] == t){
        xs[cur][b][64+dl] = hh;     // own hl for t+2 (li==t case)
        clb[cur][b][dl]   = cc;     // own cl for t+2
      }
    } else if (kg == 2){            // emb(t+1) -> label slots
      if (t+1 < D){
        const int b = lane>>5, jj = lane&31;
        const int row = labels[(t+1)*256 + gb0 + b];
        const float2 ev = *(const float2*)(emb + (size_t)row*LD + jj*2);
        xs[nxt][b][jj*2]   = ev.x;
        xs[nxt][b][jj*2+1] = ev.y;
      }
    } else if (kg == 3){            // own-half hl/cl for t+1
      if (t+1 < D){
        const int b = lane>>5, jj = lane&31;
        const int m1 = mS[t+1][b]; const int li = liA[t+1][b];
        if (m1){
          if (li <= t-2){
            const size_t ro = (((size_t)li*128+g2)*2 + sl)*128 + b*64 + jj*2;
            union{u64t u; float f[2];} h_, c_;
            h_.u = gld64(rec + ro);
            c_.u = gld64(cown + ro);
            xs[nxt][b][64+jj*2]   = h_.f[0];
            xs[nxt][b][64+jj*2+1] = h_.f[1];
            clb[nxt][b][jj*2]     = c_.f[0];
            clb[nxt][b][jj*2+1]   = c_.f[1];
          }
          // li == t-1: cell@t-1 already wrote xs/clb from registers
        } else {
          xs[nxt][b][64+jj*2]   = lshd[sl*64+jj*2];
          xs[nxt][b][64+jj*2+1] = lshd[sl*64+jj*2+1];
          clb[nxt][b][jj*2]     = lshd[sl*64+jj*2];
          clb[nxt][b][jj*2+1]   = lshd[sl*64+jj*2+1];
        }
      }
    } else if (kg == 4){            // partner-half hl for t+1
      if (t+1 < D){
        const int b = lane>>5, jj = lane&31;
        const int m1 = mS[t+1][b]; const int li = liA[t+1][b];
        if (m1){
          if (li <= t-2){
            const size_t ro = (((size_t)li*128+g2)*2 + ps)*128 + b*64 + jj*2;
            union{u64t u; float f[2];} h_;
            h_.u = gld64(rec + ro);
            xs[nxt][b][128+jj*2]   = h_.f[0];
            xs[nxt][b][128+jj*2+1] = h_.f[1];
          } else {                  // li == t-1: slot confirmed by P1(t) polls
            const u64t* rp = ring + (((size_t)((t-1)&7)*128 + g2)*2 + ps)*128
                             + b*64 + jj*2;
            xs[nxt][b][128+jj*2]   = loww(gld64r(rp));
            xs[nxt][b][128+jj*2+1] = loww(gld64r(rp+1));
          }
        } else {
          xs[nxt][b][128+jj*2]   = lshd[ps*64+jj*2];
          xs[nxt][b][128+jj*2+1] = lshd[ps*64+jj*2+1];
        }
      }
    }
    BARRIER();
  }
}

extern "C" void kernel_launch(void* const* d_in, const int* in_sizes, int n_in,
                              void* d_out, int out_size, void* d_ws, size_t ws_size,
                              hipStream_t stream) {
  (void)in_sizes; (void)n_in; (void)out_size; (void)ws_size;
  const int*   trans  = (const int*)d_in[0];
  const int*   labels = (const int*)d_in[1];
  const float* emb    = (const float*)d_in[2];
  const float* W      = (const float*)d_in[3];
  const float* bias   = (const float*)d_in[4];
  const float* leaf   = (const float*)d_in[5];
  float* out = (float*)d_out;

  // ws: [0,8MB)   ring: 8-deep self-tagged h records (tag=t+1; poison/zero
  //               never match; reuse distance 8 steps, pair skew <=1 -> safe)
  //     [8MB,72MB)   rec:  h records (agent stores/loads, >=2-step-old reads)
  //     [72MB,136MB) cown: c records (own-block readers only)
  uint8_t* ws = (uint8_t*)d_ws;
  u64t*  ring = (u64t*)ws;
  float* rec  = (float*)(ws + ((size_t)8<<20));
  float* cown = (float*)(ws + ((size_t)72<<20));

  spinn_kernel<<<dim3(256), dim3(NTHR), 0, stream>>>(
      trans, labels, emb, W, bias, leaf, out, ring, rec, cown);
}

// Round 5
// 2133.056 us; speedup vs baseline: 2.1383x; 1.0426x over previous
//
#include <hip/hip_runtime.h>
#include <stdint.h>

// SPINN thin-stack TreeLSTM, MI355X, round 11: round-8 base + FORCED W
// register residency. Theory: r6/r8/r10 were L2-BW-bound re-streaming W
// every step (VGPR=128 < 200 W floats; FETCH too small for spills -> the
// compiler rematerialized W loads from L2-hot global; 52GB/dispatch ~ 27TB/s
// ~ L2 ceiling explains dur + low VALUBusy). Fix, one variable vs r8:
//  (a) launch_bounds(512,1) + amdgpu_waves_per_eu(1,2): register cap = the
//      2-waves/SIMD budget, allocator must not squeeze to 4 waves/EU
//      (grid = 256 = 1 block/CU regardless, so occupancy is unchanged);
//  (b) empty-asm "+v" pin on all 200 W values after the pre-loop load:
//      values become opaque -> no rematerialization, must stay in regs
//      (arch or AGPR; gfx950 VALU reads AGPRs directly).
// Everything else byte-identical to the verified round-8 kernel (1934us,
// stable dispatches): 2-phase schedule, self-tagged 8-deep ring exchange,
// in-phase P2 poll with s_sleep, __syncthreads barriers.

#define D     512
#define HD    128
#define LD    64
#define NTHR  512
#define GPR   328   // gp row stride (floats): 256 quad cols + 64 u cols + pad

typedef unsigned long long u64t;

__device__ __forceinline__ float sigf(float x){ return 1.0f/(1.0f+__expf(-x)); }
__device__ __forceinline__ float tanh_(float x){ return 1.0f-2.0f/(__expf(2.0f*x)+1.0f); }
__device__ __forceinline__ u64t gld64(const float* p){
  return __hip_atomic_load((const u64t*)p, __ATOMIC_RELAXED, __HIP_MEMORY_SCOPE_AGENT);
}
__device__ __forceinline__ u64t gld64r(const u64t* p){
  return __hip_atomic_load(p, __ATOMIC_RELAXED, __HIP_MEMORY_SCOPE_AGENT);
}
__device__ __forceinline__ void gst32(float* p, float v){
  __hip_atomic_store(p, v, __ATOMIC_RELAXED, __HIP_MEMORY_SCOPE_AGENT);
}
__device__ __forceinline__ void gst64r(u64t* p, u64t v){
  __hip_atomic_store(p, v, __ATOMIC_RELAXED, __HIP_MEMORY_SCOPE_AGENT);
}
__device__ __forceinline__ u64t packw(float v, unsigned tg){
  return ((u64t)tg << 32) | (u64t)__float_as_uint(v);
}
__device__ __forceinline__ float loww(u64t w){
  return __uint_as_float((unsigned)(w & 0xffffffffu));
}

__global__ void __launch_bounds__(NTHR, 1)
__attribute__((amdgpu_waves_per_eu(1, 2)))
spinn_kernel(
    const int* __restrict__ trans, const int* __restrict__ labels,
    const float* __restrict__ emb, const float* __restrict__ W,
    const float* __restrict__ bias, const float* __restrict__ leaf,
    float* __restrict__ out, u64t* __restrict__ ring,
    float* __restrict__ rec, float* __restrict__ cown)
{
  const int bid = blockIdx.x;
  const int g2 = bid>>1, sl = bid&1, ps = sl^1;
  const int gb0 = g2*2;
  const int tid = threadIdx.x;
  const int kg = tid>>6, lane = tid&63;
  const int cq = lane;

  __shared__ __align__(16) float xs[2][2][320];     // [buf][b][k]: 64 lab|128 hl|128 hr
  __shared__ __align__(16) float gpq[16][GPR];      // [(kg*2+b)][col]
  __shared__ float bsl[320];
  __shared__ float lshd[HD];
  __shared__ float clb[2][2][64];
  __shared__ uint8_t mS[D][2];
  __shared__ short liA[D][2];
  __shared__ unsigned short stk_[2][D];

  // --- W slice into registers: 40 K-rows x (4 quad cols + 1 u col) ---
  float4 wr4[40]; float wr1[40];
  {
    const int gq = (cq>>4)*128 + sl*64 + ((cq*4)&63);  // quad base (gates 0-3)
    const int gu = 512 + sl*64 + cq;                   // u-gate col
#pragma unroll
    for (int j=0;j<40;++j){
      int k = kg*40 + j;
      wr4[j] = *(const float4*)(W + (size_t)k*640 + gq);
      wr1[j] = W[(size_t)k*640 + gu];
    }
  }
  // PIN: make every W value opaque so the backend cannot rematerialize the
  // global loads inside the t-loop (the r6/r8/r10 L2-streaming failure mode).
#pragma unroll
  for (int j=0;j<40;++j){
    asm volatile("" : "+v"(wr4[j].x), "+v"(wr4[j].y),
                      "+v"(wr4[j].z), "+v"(wr4[j].w), "+v"(wr1[j]));
  }
  if (tid < 320){
    int c = tid;
    int gc = (c < 256) ? ((c>>6)*128 + sl*64 + (c&63)) : (512 + sl*64 + (c-256));
    bsl[c] = bias[gc];
  }
  if (tid < HD) lshd[tid] = leaf[tid];
  if (tid < 2){   // precompute (mask, li); ri == t-1 always on a reduce
    int b = tid, p = 0;
    for (int t=0;t<D;++t){
      int m = trans[t*256 + gb0 + b];
      short li = 0;
      if (m) li = (short)stk_[b][p-2];
      mS[t][b] = (uint8_t)m; liA[t][b] = li;
      int np = p - 2*m; stk_[b][np] = (unsigned short)t; p = np+1;
    }
  }
  __syncthreads();

  // --- prefill xs[0]: emb(labels[0]) + leaf (mask(0)==0 by construction) ---
  for (int idx = tid; idx < 640; idx += NTHR){
    int b = (idx >= 320) ? 1 : 0;
    int r = idx - b*320;
    if (r < 64){
      int row = labels[gb0 + b];
      xs[0][b][r] = emb[(size_t)row*LD + r];
    } else {
      xs[0][b][r] = lshd[(r-64)&127];
    }
  }
  __syncthreads();

  auto gemm = [&](int cur){
    float4 a0 = {0.f,0.f,0.f,0.f}, a1 = {0.f,0.f,0.f,0.f};
    float u0 = 0.f, u1 = 0.f;
#pragma unroll
    for (int j4=0;j4<10;++j4){
      int k = kg*40 + j4*4;
      float4 x0 = *(const float4*)&xs[cur][0][k];   // broadcast (all lanes same)
      float4 x1 = *(const float4*)&xs[cur][1][k];
      float xa0[4] = {x0.x,x0.y,x0.z,x0.w};
      float xa1[4] = {x1.x,x1.y,x1.z,x1.w};
#pragma unroll
      for (int jj=0;jj<4;++jj){
        float4 w = wr4[j4*4+jj];
        float wu = wr1[j4*4+jj];
        a0.x = __builtin_fmaf(w.x, xa0[jj], a0.x);
        a0.y = __builtin_fmaf(w.y, xa0[jj], a0.y);
        a0.z = __builtin_fmaf(w.z, xa0[jj], a0.z);
        a0.w = __builtin_fmaf(w.w, xa0[jj], a0.w);
        a1.x = __builtin_fmaf(w.x, xa1[jj], a1.x);
        a1.y = __builtin_fmaf(w.y, xa1[jj], a1.y);
        a1.z = __builtin_fmaf(w.z, xa1[jj], a1.z);
        a1.w = __builtin_fmaf(w.w, xa1[jj], a1.w);
        u0 = __builtin_fmaf(wu, xa0[jj], u0);
        u1 = __builtin_fmaf(wu, xa1[jj], u1);
      }
    }
    *(float4*)&gpq[kg*2+0][cq*4] = a0;
    *(float4*)&gpq[kg*2+1][cq*4] = a1;
    gpq[kg*2+0][256+cq] = u0;
    gpq[kg*2+1][256+cq] = u1;
  };

  float ccprev = 0.f;   // own c[t-1][b][dl] (cell threads only)

  for (int t=0;t<D;++t){
    const int cur = t&1, nxt = cur^1;

    // ---- P1: ALL 8 waves GEMM the full K=320 (xs[cur] complete) ----
    gemm(cur);
    __syncthreads();

    // ---- P2: cell (waves 0-1) || prefetch t+1 (2,3,6) || exchange (7) ----
    if (tid < 128){
      const int b = tid>>6, dl = tid&63, gd = sl*64+dl;
      const int m = mS[t][b];
      float s[5];
#pragma unroll
      for (int g=0; g<5; ++g){
        int c = (g<4) ? (g*64+dl) : (256+dl);
        float a = 0.f;
#pragma unroll
        for (int kk=0; kk<8; ++kk) a += gpq[kk*2+b][c];
        s[g] = a + bsl[c];
      }
      float cl_ = m ? clb[cur][b][dl] : lshd[gd];
      float cr_ = m ? ccprev : lshd[gd];            // ri == t-1: own prev c
      float cc = sigf(s[0])*tanh_(s[4]) + sigf(s[1])*cl_ + sigf(s[2])*cr_;
      float hh = sigf(s[3])*tanh_(cc);
      ccprev = cc;
      // publish self-tagged h FIRST (partner polls it at its P2(t))
      gst64r(ring + (((size_t)(t&7)*128 + g2)*2 + sl)*128 + tid,
             packw(hh, (unsigned)(t+1)));
      size_t ro = (((size_t)t*128 + g2)*2 + sl)*128 + b*64 + dl;
      gst32(rec + ro, hh);
      gst32(cown + ro, cc);
      if (t == D-1){
        out[(size_t)(gb0+b)*HD + gd] = cc;
        out[(size_t)256*HD + (size_t)(gb0+b)*HD + gd] = hh;
      } else {
        xs[nxt][b][192+gd] = mS[t+1][b] ? hh : lshd[gd];   // own hr for t+1
      }
      if (t+2 < D && mS[t+2][b] && liA[t+2][b] == t){
        xs[cur][b][64+gd]  = hh;    // own hl for t+2 (li==t case)
        clb[cur][b][dl]    = cc;    // own cl for t+2
      }
    } else if (kg == 2){            // emb(t+1)
      if (t+1 < D){
        int b = lane>>5, jj = lane&31;
        int row = labels[(t+1)*256 + gb0 + b];
        float2 ev = *(const float2*)(emb + (size_t)row*LD + jj*2);
        xs[nxt][b][jj*2]   = ev.x;
        xs[nxt][b][jj*2+1] = ev.y;
      }
    } else if (kg == 3){            // own-slice hl/cl for t+1
      if (t+1 < D){
        int b = lane>>5, jj = lane&31;
        int m1 = mS[t+1][b]; int li = liA[t+1][b];
        if (m1){
          if (li <= t-2){
            size_t ro = (((size_t)li*128+g2)*2 + sl)*128 + b*64 + jj*2;
            union{u64t u; float f[2];} h_, c_;
            h_.u = gld64(rec + ro);
            c_.u = gld64(cown + ro);
            xs[nxt][b][64+sl*64+jj*2]   = h_.f[0];
            xs[nxt][b][64+sl*64+jj*2+1] = h_.f[1];
            clb[nxt][b][jj*2]   = c_.f[0];
            clb[nxt][b][jj*2+1] = c_.f[1];
          }
          // li == t-1: cell@t-1 already wrote xs/clb from registers
        } else {
          xs[nxt][b][64+sl*64+jj*2]   = lshd[sl*64+jj*2];
          xs[nxt][b][64+sl*64+jj*2+1] = lshd[sl*64+jj*2+1];
          clb[nxt][b][jj*2]   = lshd[sl*64+jj*2];
          clb[nxt][b][jj*2+1] = lshd[sl*64+jj*2+1];
        }
      }
    } else if (kg == 6){            // partner-slice hl for t+1
      if (t+1 < D){
        int b = lane>>5, jj = lane&31;
        int m1 = mS[t+1][b]; int li = liA[t+1][b];
        if (m1){
          if (li <= t-2){
            size_t ro = (((size_t)li*128+g2)*2 + ps)*128 + b*64 + jj*2;
            union{u64t u; float f[2];} h_;
            h_.u = gld64(rec + ro);
            xs[nxt][b][64+ps*64+jj*2]   = h_.f[0];
            xs[nxt][b][64+ps*64+jj*2+1] = h_.f[1];
          } else {                  // li == t-1: ring slot confirmed at P2(t-1)
            const u64t* rp = ring + (((size_t)((t-1)&7)*128 + g2)*2 + ps)*128
                             + b*64 + jj*2;
            xs[nxt][b][64+ps*64+jj*2]   = loww(gld64r(rp));
            xs[nxt][b][64+ps*64+jj*2+1] = loww(gld64r(rp+1));
          }
        } else {
          xs[nxt][b][64+ps*64+jj*2]   = lshd[ps*64+jj*2];
          xs[nxt][b][64+ps*64+jj*2+1] = lshd[ps*64+jj*2+1];
        }
      }
    } else if (kg == 7){            // poll partner h(t); deposit hr for t+1
      if (t+1 < D){
        const u64t* rp = ring + (((size_t)(t&7)*128 + g2)*2 + ps)*128 + lane*2;
        const unsigned want = (unsigned)(t+1);
        u64t w0 = 0, w1 = 0; int it = 0;
        for (;;){
          w0 = gld64r(rp); w1 = gld64r(rp+1);
          int ok = ((unsigned)(w0>>32) == want) & ((unsigned)(w1>>32) == want);
          if (__all(ok)) break;
          __builtin_amdgcn_s_sleep(1);
          if (++it > (1<<20)) break;   // safety: hang -> wrong answer
        }
        int b = lane>>5, jj = lane&31;
        if (mS[t+1][b]){
          xs[nxt][b][192+ps*64+jj*2]   = loww(w0);
          xs[nxt][b][192+ps*64+jj*2+1] = loww(w1);
        } else {
          xs[nxt][b][192+ps*64+jj*2]   = lshd[ps*64+jj*2];
          xs[nxt][b][192+ps*64+jj*2+1] = lshd[ps*64+jj*2+1];
        }
      }
    }
    __syncthreads();
  }
}

extern "C" void kernel_launch(void* const* d_in, const int* in_sizes, int n_in,
                              void* d_out, int out_size, void* d_ws, size_t ws_size,
                              hipStream_t stream) {
  (void)in_sizes; (void)n_in; (void)out_size; (void)ws_size;
  const int*   trans  = (const int*)d_in[0];
  const int*   labels = (const int*)d_in[1];
  const float* emb    = (const float*)d_in[2];
  const float* W      = (const float*)d_in[3];
  const float* bias   = (const float*)d_in[4];
  const float* leaf   = (const float*)d_in[5];
  float* out = (float*)d_out;

  // ws: [0, 2MB)   ring: 8-deep self-tagged h records, u64 per (slot,g2,sl,b,dl)
  //               (tag = t+1: 0xAA poison AND zero-init != any live tag;
  //                slot reuse distance 8 steps, pair skew <=1 step -> safe)
  //     [8MB,72MB)  rec:  plain h records (li<=t-2 readers, >=2 steps old)
  //     [72MB,136MB) cown: plain c records (own-block readers only)
  uint8_t* ws = (uint8_t*)d_ws;
  u64t*  ring = (u64t*)ws;
  float* rec  = (float*)(ws + ((size_t)8<<20));
  float* cown = (float*)(ws + ((size_t)72<<20));

  spinn_kernel<<<dim3(256), dim3(NTHR), 0, stream>>>(
      trans, labels, emb, W, bias, leaf, out, ring, rec, cown);
}